// Round 17
// baseline (3027.074 us; speedup 1.0000x reference)
//
#include <hip/hip_runtime.h>

// WeatherLSTM: B=256, T=128, I=64, H=2048, O=24
// R17 = R16 (i8 W + dual-i8 h/x, exact i32 MFMA) with:
//  (a) parallel colmax (128x8 partial + reduce) : 130us -> ~18us
//  (b) tile 64 rows x 128 pcols, BOTH operands DMA->LDS: per-CU ingress
//      660 -> 540 KB/step (A 64x2112x2B = 270KB, B 128x2112x1B = 270KB),
//      4 vm-instr/wave/iter. Distinguishes ingress-wall vs W-refetch-wall.
// LDS: 6 bufs x 16KB (A 8K: [s2][rb2][hl2], B 8K: [cb2][kg4]) + gH/gX 64KB.

#define NB 256
#define NH 2048
#define NI 64
#define NK 2112
#define NPK 8192
#define NSTEPS 151
#define NO 24

typedef int i32x4 __attribute__((ext_vector_type(4)));
typedef int i32x16 __attribute__((ext_vector_type(16)));
typedef float f32x4 __attribute__((ext_vector_type(4)));
typedef unsigned short u16;
typedef unsigned char u8;
typedef unsigned long long u64;

__device__ __forceinline__ void gload16(const void* g, void* l) {
  __builtin_amdgcn_global_load_lds(
      (const __attribute__((address_space(1))) unsigned int*)g,
      (__attribute__((address_space(3))) unsigned int*)l, 16, 0, 0);
}

__device__ __forceinline__ int q8(float v) {
  int q = __float2int_rn(v);
  return q > 127 ? 127 : (q < -127 ? -127 : q);
}

__device__ __forceinline__ float sigmoidf_(float x) { return 1.f / (1.f + __expf(-x)); }
__device__ __forceinline__ float tanhf_(float x) {
  x = fminf(15.f, fmaxf(-15.f, x));
  float e = __expf(2.f * x);
  return (e - 1.f) / (e + 1.f);
}

// ---- colmax pass 1: partial per (j-block, k-block) -> pmax[kb][j]
__global__ __launch_bounds__(256) void wl_colmax1(const float* __restrict__ Wx,
                                                  const float* __restrict__ Wh,
                                                  float* __restrict__ pmax) {
  __shared__ float red[4][64];
  const int jl = threadIdx.x & 63, ks = threadIdx.x >> 6;
  const int j = blockIdx.x * 64 + jl;
  const int k0 = blockIdx.y * 264 + ks * 66;
  float m = 0.f;
  for (int i = 0; i < 66; ++i) {
    int k = k0 + i;
    float v = (k < NH) ? Wh[(size_t)k * NPK + j] : Wx[(size_t)(k - NH) * NPK + j];
    m = fmaxf(m, fabsf(v));
  }
  red[ks][jl] = m;
  __syncthreads();
  if (ks == 0)
    pmax[(size_t)blockIdx.y * NPK + j] =
        fmaxf(fmaxf(red[0][jl], red[1][jl]), fmaxf(red[2][jl], red[3][jl]));
}

// ---- colmax pass 2: sp[p] = max/127, rq[p] = 127/max
__global__ __launch_bounds__(256) void wl_colmax2(const float* __restrict__ pmax,
                                                  float* __restrict__ sp,
                                                  float* __restrict__ rq) {
  int p = blockIdx.x * 256 + threadIdx.x;
  int j = (p >> 2) | ((p & 3) << 11);
  float m = 0.f;
#pragma unroll
  for (int kb = 0; kb < 8; ++kb) m = fmaxf(m, pmax[(size_t)kb * NPK + j]);
  sp[p] = m * (1.f / 127.f);
  rq[p] = (m > 0.f) ? 127.f / m : 0.f;
}

// ---- pack [Wh;Wx] -> Wq i8 [csq 128][kt 33][kg 4][col 64][e 16]
__global__ __launch_bounds__(256) void wl_pack_w(const float* __restrict__ Wx,
                                                 const float* __restrict__ Wh,
                                                 const float* __restrict__ rq,
                                                 u8* __restrict__ Wq) {
  __shared__ float s[64][65];
  const int j0 = blockIdx.x * 64, k0 = blockIdx.y * 64;  // grid (128, 33)
  const int jl = threadIdx.x & 63, kg = threadIdx.x >> 6;
#pragma unroll
  for (int it = 0; it < 16; ++it) {
    int kl = it * 4 + kg;
    int k = k0 + kl, j = j0 + jl;
    float v = (k < NH) ? Wh[(size_t)k * NPK + j] : Wx[(size_t)(k - NH) * NPK + j];
    s[kl][jl] = v;
  }
  __syncthreads();
  const int j = j0 + jl;
  const int p = (j & (NH - 1)) * 4 + (j >> 11);
  const int csq = p >> 6, col = p & 63;
  const float r = rq[p];
  union { u8 b[16]; i32x4 v; } q;
#pragma unroll
  for (int e = 0; e < 16; ++e) q.b[e] = (u8)(signed char)q8(s[kg * 16 + e][jl] * r);
  *(i32x4*)(Wq + ((size_t)(csq * 33 + blockIdx.y) * 4 + kg) * 1024 + col * 16) = q.v;
}

__global__ __launch_bounds__(256) void wl_bsum(const float* __restrict__ bx,
                                               const float* __restrict__ bh,
                                               float* __restrict__ bsum) {
  int p = blockIdx.x * 256 + threadIdx.x;
  int j = (p & 3) * NH + (p >> 2);
  bsum[p] = bx[j] + bh[j];
}

// ---- x: dual-i8 per (t,b) row; xfH/xfL [t][rb 8][kc 2][lane 64][16]
__global__ __launch_bounds__(256) void wl_xall(const float* __restrict__ trains,
                                               const float* __restrict__ dec,
                                               const float* __restrict__ Win,
                                               const float* __restrict__ b_in,
                                               u8* __restrict__ xfH,
                                               u8* __restrict__ xfL,
                                               float* __restrict__ sx) {
  const int t = blockIdx.x, b = threadIdx.x;
  float x[64];
  if (t < 128) {
    const float4* src = (const float4*)(trains + ((size_t)b * 128 + t) * 64);
#pragma unroll
    for (int i = 0; i < 16; ++i) {
      float4 v = src[i];
      x[4 * i] = v.x; x[4 * i + 1] = v.y; x[4 * i + 2] = v.z; x[4 * i + 3] = v.w;
    }
  } else {
    float d = dec[b * 23 + (t - 128)];
#pragma unroll
    for (int i = 0; i < 64; ++i) x[i] = d * Win[i] + b_in[i];
  }
  float m = 0.f;
#pragma unroll
  for (int i = 0; i < 64; ++i) m = fmaxf(m, fabsf(x[i]));
  float sv, r;
  if (m > 1e-30f) { sv = m * (1.f / 127.f); r = 127.f / m; }
  else            { sv = 1.f; r = 0.f; }
  sx[t * 256 + b] = sv;
  const size_t base = (size_t)t * 16384 + (b >> 5) * 2048;
#pragma unroll
  for (int kc = 0; kc < 2; ++kc)
#pragma unroll
    for (int lhh = 0; lhh < 2; ++lhh) {
      union { u8 b16[16]; i32x4 v; } wh, wl;
#pragma unroll
      for (int e = 0; e < 16; ++e) {
        float xs = x[kc * 32 + lhh * 16 + e] * r;
        int hi = q8(xs);
        int lo = q8((xs - (float)hi) * 254.f);
        wh.b16[e] = (u8)(signed char)hi;
        wl.b16[e] = (u8)(signed char)lo;
      }
      size_t off = base + kc * 1024 + (lhh * 32 + (b & 31)) * 16;
      *(i32x4*)(xfH + off) = wh.v;
      *(i32x4*)(xfL + off) = wl.v;
    }
}

// ---- one step. 256 blocks x 256 threads (4 waves). Tile 64 rows x 128 pcols.
// cs = (bid&7)*8 + ((bid>>3)&7) in 0..63, rh = bid>>6 in 0..3 (same-cs blocks
// share an XCD -> B L2-dedupe). Wave wv: all 64 rows x cols [wv*32,+32).
// A (dual-i8) and B (i8) both DMA->LDS; mfma_i32_32x32x32_i8.
__global__ __launch_bounds__(256, 1) void wl_step(const u8* __restrict__ Wq,
                                                  const float* __restrict__ bsum,
                                                  const float* __restrict__ sp,
                                                  const u8* __restrict__ xfH,
                                                  const u8* __restrict__ xfL,
                                                  const float* __restrict__ sx,
                                                  u8* __restrict__ hfH,    // 2 bufs
                                                  u8* __restrict__ hfL,    // 2 bufs
                                                  float* __restrict__ c_t, // [u][b]
                                                  float* __restrict__ ypart,
                                                  const float* __restrict__ Wout,
                                                  int t) {
  __shared__ char arena[163840];  // 6 bufs x 16KB | gH 32KB @98304 | gX @131072

  const int bid = blockIdx.x;
  const int cs = (bid & 7) * 8 + ((bid >> 3) & 7);  // col-slice 0..63 (128 pcols)
  const int rh = bid >> 6;                          // row quarter 0..3
  const int p0 = cs * 128, u0 = cs * 32, b0 = rh * 64;
  const int rbg = rh * 2;                           // first 32-row frag block

  const int tid = threadIdx.x;
  const int wv = tid >> 6, lane = tid & 63;
  const int l31 = lane & 31, lh = lane >> 5;

  const int par = t & 1;
  const u8* __restrict__ hinH = hfH + (size_t)par * 524288;
  const u8* __restrict__ hinL = hfL + (size_t)par * 524288;
  u8* __restrict__ houtH = hfH + (size_t)(par ^ 1) * 524288;
  u8* __restrict__ houtL = hfL + (size_t)(par ^ 1) * 524288;

  i32x16 aHh[2] = {}, aHl[2] = {}, aXh[2] = {}, aXl[2] = {};

  // stage tile kt: A 8KB (chunk c<8: s=c>>2, rb=(c>>1)&1, hl=c&1) +
  //                B 8KB (chunk c>=8: cb=(c>>2)&1, kg=c&3); 4 DMA/wave.
  auto stage = [&](int kt, int buf) {
    char* const base = arena + buf * 16384;
#pragma unroll
    for (int i = 0; i < 4; ++i) {
      int c = wv * 4 + i;
      const u8* src;
      char* dst;
      if (c < 8) {
        int s = c >> 2, rb = (c >> 1) & 1, hl = c & 1;
        const u8* hb = hl ? hinL : hinH;
        const u8* xb = hl ? xfL : xfH;
        src = (kt < 32)
                  ? hb + ((size_t)(rbg + rb) * 64 + 2 * kt + s) * 1024
                  : xb + (size_t)t * 16384 + (rbg + rb) * 2048 + s * 1024;
        dst = base + c * 1024;
      } else {
        int cb = (c >> 2) & 1, kg = c & 3;
        src = Wq + ((size_t)((cs * 2 + cb) * 33 + kt) * 4 + kg) * 1024;
        dst = base + 8192 + ((cb << 2) + kg) * 1024;
      }
      gload16(src + lane * 16, dst);
    }
  };

  auto compute = [&](int kt, int buf) {
    const char* Ab = arena + buf * 16384;
    const char* Bb = Ab + 8192;
    const int cb = wv >> 1, cl = (wv & 1) * 32 + l31;
#pragma unroll
    for (int s = 0; s < 2; ++s) {
      i32x4 bf = *(const i32x4*)(Bb + ((cb << 2) + (s << 1) + lh) * 1024 + cl * 16);
#pragma unroll
      for (int m = 0; m < 2; ++m) {
        i32x4 ah = *(const i32x4*)(Ab + (s * 4 + m * 2 + 0) * 1024 + lane * 16);
        i32x4 al = *(const i32x4*)(Ab + (s * 4 + m * 2 + 1) * 1024 + lane * 16);
        if (kt < 32) {
          aHh[m] = __builtin_amdgcn_mfma_i32_32x32x32_i8(ah, bf, aHh[m], 0, 0, 0);
          aHl[m] = __builtin_amdgcn_mfma_i32_32x32x32_i8(al, bf, aHl[m], 0, 0, 0);
        } else {
          aXh[m] = __builtin_amdgcn_mfma_i32_32x32x32_i8(ah, bf, aXh[m], 0, 0, 0);
          aXl[m] = __builtin_amdgcn_mfma_i32_32x32x32_i8(al, bf, aXl[m], 0, 0, 0);
        }
      }
    }
  };

  // prologue: tiles 0..3 staged (16 DMA/wave)
  stage(0, 0); stage(1, 1); stage(2, 2); stage(3, 3);
#pragma unroll
  for (int kt = 0; kt < 33; ++kt) {
    if (kt + 4 <= 32) stage(kt + 4, (kt + 4) % 6);   // 4 ops/wave
    // wait tile kt resident: newer = tiles kt+1..min(32,kt+4), 4 ops each
    if (kt <= 28)      asm volatile("s_waitcnt vmcnt(16)" ::: "memory");
    else if (kt == 29) asm volatile("s_waitcnt vmcnt(12)" ::: "memory");
    else if (kt == 30) asm volatile("s_waitcnt vmcnt(8)" ::: "memory");
    else if (kt == 31) asm volatile("s_waitcnt vmcnt(4)" ::: "memory");
    else               asm volatile("s_waitcnt vmcnt(0)" ::: "memory");
    asm volatile("s_barrier" ::: "memory");  // tile kt in LDS (all waves); all
                                             // waves past compute(kt-1)
    compute(kt, kt % 6);
  }

  // ---- spill: gH = (sp/127)(aHh + aHl/254), gX = sp(aXh + aXl/254)
  // gtile [col 128][16 chunks(row>>2) x 16B], chunk ^ (col&15) swizzle
  {
    char* const gH = arena + 98304;
    char* const gX = arena + 131072;
    const int col = wv * 32 + l31;
    const float spc = sp[p0 + col];
    const float fH = spc * (1.f / 127.f);
#pragma unroll
    for (int m = 0; m < 2; ++m)
#pragma unroll
      for (int q = 0; q < 4; ++q) {
        f32x4 vH, vX;
#pragma unroll
        for (int e = 0; e < 4; ++e) {
          vH[e] = fH * ((float)aHh[m][4 * q + e] + (float)aHl[m][4 * q + e] * (1.f / 254.f));
          vX[e] = spc * ((float)aXh[m][4 * q + e] + (float)aXl[m][4 * q + e] * (1.f / 254.f));
        }
        int chunk = m * 8 + q * 2 + lh;  // row>>2; row = m*32 + q*8 + lh*4
        *(f32x4*)(gH + col * 256 + ((chunk ^ (col & 15)) << 4)) = vH;
        *(f32x4*)(gX + col * 256 + ((chunk ^ (col & 15)) << 4)) = vX;
      }
  }
  __syncthreads();

  // ---- gates + state: thread -> (row bl 0..63, unit-group ug 0..3 of 8 units)
  {
    const char* const gH = arena + 98304;
    const char* const gX = arena + 131072;
    const int bl = tid & 63, ug = tid >> 6;
    const int bg = b0 + bl;
    const float sxv = sx[t * 256 + bg];
    const bool emit = (t >= 127);
    float yacc = 0.f;
    union { u8 q[8]; u64 v; } hqh, hql;
#pragma unroll
    for (int j = 0; j < 8; ++j) {
      int ul = ug * 8 + j;                 // local unit 0..31
      float g[4];
#pragma unroll
      for (int gi = 0; gi < 4; ++gi) {
        int col = ul * 4 + gi;             // 0..127
        int off = col * 256 + (((bl >> 2) ^ (col & 15)) << 4) + (bl & 3) * 4;
        g[gi] = *(const float*)(gH + off) + sxv * *(const float*)(gX + off);
      }
      const float4 bs = *(const float4*)(bsum + p0 + ul * 4);
      float si = sigmoidf_(g[0] + bs.x);
      float sf = sigmoidf_(g[1] + bs.y);
      float so = sigmoidf_(g[2] + bs.z);
      float tc = tanhf_(g[3] + bs.w);
      size_t ci = (size_t)(u0 + ul) * NB + bg;
      float cn = sf * c_t[ci] + si * tc;
      float h = so * tanhf_(cn);
      c_t[ci] = cn;
      float hs = h * 127.f;
      int hi = q8(hs);
      int lo = q8((hs - (float)hi) * 254.f);
      hqh.q[j] = (u8)(signed char)hi;
      hql.q[j] = (u8)(signed char)lo;
      if (emit) yacc += h * Wout[u0 + ul];
    }
    // h -> fragment layout: rb=bg>>5, kc32=cs, lane=(ug>>1)*32+(bg&31), e=(ug&1)*8+j
    size_t hoff = ((size_t)((bg >> 5) * 64 + cs) * 64 +
                   (ug >> 1) * 32 + (bg & 31)) * 16 + (ug & 1) * 8;
    *(u64*)(houtH + hoff) = hqh.v;
    *(u64*)(houtL + hoff) = hql.v;
    if (emit) ypart[((size_t)(t - 127) * 256 + cs * 4 + ug) * NB + bg] = yacc;
  }
}

// ---- y[b][j] = bout + sum_{s<256} ypart[j][s][b]
__global__ __launch_bounds__(256) void wl_finy(const float* __restrict__ ypart,
                                               const float* __restrict__ bout,
                                               float* __restrict__ out) {
  int j = blockIdx.x;
  int b = threadIdx.x;
  const float* yp = ypart + (size_t)j * 256 * NB;
  float s = bout[0];
#pragma unroll 8
  for (int i = 0; i < 256; ++i) s += yp[i * NB + b];
  out[b * NO + j] = s;
}

extern "C" void kernel_launch(void* const* d_in, const int* in_sizes, int n_in,
                              void* d_out, int out_size, void* d_ws, size_t ws_size,
                              hipStream_t stream) {
  const float* trains = (const float*)d_in[0];
  const float* dec    = (const float*)d_in[1];
  const float* Wx     = (const float*)d_in[2];
  const float* bx     = (const float*)d_in[3];
  const float* Wh     = (const float*)d_in[4];
  const float* bh     = (const float*)d_in[5];
  const float* Win    = (const float*)d_in[6];
  const float* b_in   = (const float*)d_in[7];
  const float* Wout   = (const float*)d_in[8];
  const float* bout   = (const float*)d_in[9];
  float* out = (float*)d_out;
  char* ws = (char*)d_ws;

  u8*    Wq    = (u8*)(ws);                   // 17,301,504
  float* sp    = (float*)(ws + 17301504);     //     32,768 -> 17,334,272
  float* rq    = (float*)(ws + 17334272);     //     32,768 -> 17,367,040
  float* bsum  = (float*)(ws + 17367040);     //     32,768 -> 17,399,808
  u8*    xfH   = (u8*)(ws + 17399808);        //  2,473,984 -> 19,873,792
  u8*    xfL   = (u8*)(ws + 19873792);        //  2,473,984 -> 22,347,776
  float* sx    = (float*)(ws + 22347776);     //    154,624 -> 22,502,400
  u8*    hfH   = (u8*)(ws + 23550976);        //  1,048,576 -> 24,599,552
  u8*    hfL   = (u8*)(ws + 24599552);        //  1,048,576 -> 25,648,128
  float* c_t   = (float*)(ws + 25648128);     //  2,097,152 -> 27,745,280
  float* ypart = (float*)(ws + 27745280);     //  6,291,456 -> 34,036,736
  float* pmax  = (float*)(ws + 34036736);     //    262,144 -> 34,298,880

  // zero hfH + hfL (both bufs) + c_t in one contiguous memset
  (void)hipMemsetAsync(ws + 23550976, 0, 4194304, stream);
  wl_colmax1<<<dim3(128, 8), 256, 0, stream>>>(Wx, Wh, pmax);
  wl_colmax2<<<32, 256, 0, stream>>>(pmax, sp, rq);
  wl_pack_w<<<dim3(128, 33), 256, 0, stream>>>(Wx, Wh, rq, Wq);
  wl_bsum<<<32, 256, 0, stream>>>(bx, bh, bsum);
  wl_xall<<<NSTEPS, 256, 0, stream>>>(trains, dec, Win, b_in, xfH, xfL, sx);
  for (int t = 0; t < NSTEPS; ++t)
    wl_step<<<256, 256, 0, stream>>>(Wq, bsum, sp, xfH, xfL, sx, hfH, hfL,
                                     c_t, ypart, Wout, t);
  wl_finy<<<NO, 256, 0, stream>>>(ypart, bout, out);
}

// Round 18
// 2390.751 us; speedup vs baseline: 1.2662x; 1.2662x over previous
//
#include <hip/hip_runtime.h>

// WeatherLSTM: B=256, T=128, I=64, H=2048, O=24
// R18 = R16's step kernel VERBATIM (measured 13.9us/step = the ~50cy/vm-instr
// /CU issue wall at 660 instr/CU/step, byte-minimal at feasible precision)
// + R17's parallel colmax (130us -> ~18us), the only R17 piece that helped.
// i8 weights (L2-resident 2.16MB/XCD) + dual-i8 activations (hi + lo/254).

#define NB 256
#define NH 2048
#define NI 64
#define NK 2112
#define NPK 8192
#define NSTEPS 151
#define NO 24

typedef int i32x4 __attribute__((ext_vector_type(4)));
typedef int i32x16 __attribute__((ext_vector_type(16)));
typedef float f32x4 __attribute__((ext_vector_type(4)));
typedef unsigned short u16;
typedef unsigned char u8;
typedef unsigned long long u64;

__device__ __forceinline__ void gload16(const void* g, void* l) {
  __builtin_amdgcn_global_load_lds(
      (const __attribute__((address_space(1))) unsigned int*)g,
      (__attribute__((address_space(3))) unsigned int*)l, 16, 0, 0);
}

__device__ __forceinline__ int q8(float v) {
  int q = __float2int_rn(v);
  return q > 127 ? 127 : (q < -127 ? -127 : q);
}

__device__ __forceinline__ float sigmoidf_(float x) { return 1.f / (1.f + __expf(-x)); }
__device__ __forceinline__ float tanhf_(float x) {
  x = fminf(15.f, fmaxf(-15.f, x));
  float e = __expf(2.f * x);
  return (e - 1.f) / (e + 1.f);
}

// ---- colmax pass 1 (parallel, R17-proven): partial max -> pmax[kb][j]
__global__ __launch_bounds__(256) void wl_colmax1(const float* __restrict__ Wx,
                                                  const float* __restrict__ Wh,
                                                  float* __restrict__ pmax) {
  __shared__ float red[4][64];
  const int jl = threadIdx.x & 63, ks = threadIdx.x >> 6;
  const int j = blockIdx.x * 64 + jl;
  const int k0 = blockIdx.y * 264 + ks * 66;
  float m = 0.f;
  for (int i = 0; i < 66; ++i) {
    int k = k0 + i;
    float v = (k < NH) ? Wh[(size_t)k * NPK + j] : Wx[(size_t)(k - NH) * NPK + j];
    m = fmaxf(m, fabsf(v));
  }
  red[ks][jl] = m;
  __syncthreads();
  if (ks == 0)
    pmax[(size_t)blockIdx.y * NPK + j] =
        fmaxf(fmaxf(red[0][jl], red[1][jl]), fmaxf(red[2][jl], red[3][jl]));
}

// ---- colmax pass 2: sp[p] = max/127, rq[p] = 127/max
__global__ __launch_bounds__(256) void wl_colmax2(const float* __restrict__ pmax,
                                                  float* __restrict__ sp,
                                                  float* __restrict__ rq) {
  int p = blockIdx.x * 256 + threadIdx.x;
  int j = (p >> 2) | ((p & 3) << 11);
  float m = 0.f;
#pragma unroll
  for (int kb = 0; kb < 8; ++kb) m = fmaxf(m, pmax[(size_t)kb * NPK + j]);
  sp[p] = m * (1.f / 127.f);
  rq[p] = (m > 0.f) ? 127.f / m : 0.f;
}

// ---- pack [Wh;Wx] -> Wq i8 [cs 128][kt 33][kg 4][col 64][e 16]
__global__ __launch_bounds__(256) void wl_pack_w(const float* __restrict__ Wx,
                                                 const float* __restrict__ Wh,
                                                 const float* __restrict__ rq,
                                                 u8* __restrict__ Wq) {
  __shared__ float s[64][65];
  const int j0 = blockIdx.x * 64, k0 = blockIdx.y * 64;  // grid (128, 33)
  const int jl = threadIdx.x & 63, kg = threadIdx.x >> 6;
#pragma unroll
  for (int it = 0; it < 16; ++it) {
    int kl = it * 4 + kg;
    int k = k0 + kl, j = j0 + jl;
    float v = (k < NH) ? Wh[(size_t)k * NPK + j] : Wx[(size_t)(k - NH) * NPK + j];
    s[kl][jl] = v;
  }
  __syncthreads();
  const int j = j0 + jl;
  const int p = (j & (NH - 1)) * 4 + (j >> 11);
  const int cs = p >> 6, col = p & 63;
  const float r = rq[p];
  union { u8 b[16]; i32x4 v; } q;
#pragma unroll
  for (int e = 0; e < 16; ++e) q.b[e] = (u8)(signed char)q8(s[kg * 16 + e][jl] * r);
  *(i32x4*)(Wq + ((size_t)(cs * 33 + blockIdx.y) * 4 + kg) * 1024 + col * 16) = q.v;
}

__global__ __launch_bounds__(256) void wl_bsum(const float* __restrict__ bx,
                                               const float* __restrict__ bh,
                                               float* __restrict__ bsum) {
  int p = blockIdx.x * 256 + threadIdx.x;
  int j = (p & 3) * NH + (p >> 2);
  bsum[p] = bx[j] + bh[j];
}

// ---- x: dual-i8 per (t,b) row; xfH/xfL [t][rb 8][kc 2][lane 64][16]
__global__ __launch_bounds__(256) void wl_xall(const float* __restrict__ trains,
                                               const float* __restrict__ dec,
                                               const float* __restrict__ Win,
                                               const float* __restrict__ b_in,
                                               u8* __restrict__ xfH,
                                               u8* __restrict__ xfL,
                                               float* __restrict__ sx) {
  const int t = blockIdx.x, b = threadIdx.x;
  float x[64];
  if (t < 128) {
    const float4* src = (const float4*)(trains + ((size_t)b * 128 + t) * 64);
#pragma unroll
    for (int i = 0; i < 16; ++i) {
      float4 v = src[i];
      x[4 * i] = v.x; x[4 * i + 1] = v.y; x[4 * i + 2] = v.z; x[4 * i + 3] = v.w;
    }
  } else {
    float d = dec[b * 23 + (t - 128)];
#pragma unroll
    for (int i = 0; i < 64; ++i) x[i] = d * Win[i] + b_in[i];
  }
  float m = 0.f;
#pragma unroll
  for (int i = 0; i < 64; ++i) m = fmaxf(m, fabsf(x[i]));
  float sv, r;
  if (m > 1e-30f) { sv = m * (1.f / 127.f); r = 127.f / m; }
  else            { sv = 1.f; r = 0.f; }
  sx[t * 256 + b] = sv;
  const size_t base = (size_t)t * 16384 + (b >> 5) * 2048;
#pragma unroll
  for (int kc = 0; kc < 2; ++kc)
#pragma unroll
    for (int lhh = 0; lhh < 2; ++lhh) {
      union { u8 b16[16]; i32x4 v; } wh, wl;
#pragma unroll
      for (int e = 0; e < 16; ++e) {
        float xs = x[kc * 32 + lhh * 16 + e] * r;
        int hi = q8(xs);
        int lo = q8((xs - (float)hi) * 254.f);
        wh.b16[e] = (u8)(signed char)hi;
        wl.b16[e] = (u8)(signed char)lo;
      }
      size_t off = base + kc * 1024 + (lhh * 32 + (b & 31)) * 16;
      *(i32x4*)(xfH + off) = wh.v;
      *(i32x4*)(xfL + off) = wl.v;
    }
}

// ---- one step (R16-proven verbatim). 256 blocks x 256 threads (4 waves, 4x1).
// Tile 128 rows x 64 pcols. cs = (bid&7)*16 + ((bid>>3)&15), rh = bid>>7.
// Wave wv: rows [b0+wv*32,+32) x all 64 pcols, mfma_i32_32x32x32_i8, dual-i8 A.
__global__ __launch_bounds__(256, 1) void wl_step(const u8* __restrict__ Wq,
                                                  const float* __restrict__ bsum,
                                                  const float* __restrict__ sp,
                                                  const u8* __restrict__ xfH,
                                                  const u8* __restrict__ xfL,
                                                  const float* __restrict__ sx,
                                                  u8* __restrict__ hfH,    // 2 bufs
                                                  u8* __restrict__ hfL,    // 2 bufs
                                                  float* __restrict__ c_t, // [u][b]
                                                  float* __restrict__ ypart,
                                                  const float* __restrict__ Wout,
                                                  int t) {
  __shared__ char arena[90112];  // 6 B-bufs x 4KB | gH 32KB @24576 | gX 32KB @57344

  const int bid = blockIdx.x;
  const int cs = (bid & 7) * 16 + ((bid >> 3) & 15);  // col-slice 0..127
  const int rh = bid >> 7;
  const int p0 = cs * 64, u0 = cs * 16, b0 = rh * 128;

  const int tid = threadIdx.x;
  const int wv = tid >> 6, lane = tid & 63;
  const int l31 = lane & 31, lh = lane >> 5;

  const int par = t & 1;
  const u8* __restrict__ hinH = hfH + (size_t)par * 524288;
  const u8* __restrict__ hinL = hfL + (size_t)par * 524288;
  u8* __restrict__ houtH = hfH + (size_t)(par ^ 1) * 524288;
  u8* __restrict__ houtL = hfL + (size_t)(par ^ 1) * 524288;

  const int rb = rh * 4 + wv;
  const size_t aoff = (size_t)rb * 65536 + lane * 16;       // + kc32*1024
  const size_t xoff = (size_t)t * 16384 + rb * 2048 + lane * 16;
  const u8* const wsrc = Wq + (size_t)cs * 135168 + wv * 1024 + lane * 16;  // + kt*4096

  i32x16 aH0h = {}, aH0l = {}, aH1h = {}, aH1l = {};
  i32x16 aX0h = {}, aX0l = {}, aX1h = {}, aX1l = {};
  i32x4 A[4][4];   // [slot][hi0,hi1,lo0,lo1]

  auto stageB = [&](int kt, int buf) {
    gload16(wsrc + (size_t)kt * 4096, arena + buf * 4096 + wv * 1024);
  };
  auto loadA = [&](int kt, int slot) {
    if (kt < 32) {
      A[slot][0] = *(const i32x4*)(hinH + aoff + (size_t)(2 * kt) * 1024);
      A[slot][1] = *(const i32x4*)(hinH + aoff + (size_t)(2 * kt + 1) * 1024);
      A[slot][2] = *(const i32x4*)(hinL + aoff + (size_t)(2 * kt) * 1024);
      A[slot][3] = *(const i32x4*)(hinL + aoff + (size_t)(2 * kt + 1) * 1024);
    } else {
      A[slot][0] = *(const i32x4*)(xfH + xoff);
      A[slot][1] = *(const i32x4*)(xfH + xoff + 1024);
      A[slot][2] = *(const i32x4*)(xfL + xoff);
      A[slot][3] = *(const i32x4*)(xfL + xoff + 1024);
    }
  };
  auto compute = [&](int kt, int buf) {
    const char* Bb = arena + buf * 4096;
    const int slot = kt & 3;
#pragma unroll
    for (int kh = 0; kh < 2; ++kh) {
      i32x4 b0 = *(const i32x4*)(Bb + (kh * 2 + lh) * 1024 + l31 * 16);
      i32x4 b1 = *(const i32x4*)(Bb + (kh * 2 + lh) * 1024 + (32 + l31) * 16);
      i32x4 ah = A[slot][kh], al = A[slot][2 + kh];
      if (kt < 32) {
        aH0h = __builtin_amdgcn_mfma_i32_32x32x32_i8(ah, b0, aH0h, 0, 0, 0);
        aH1h = __builtin_amdgcn_mfma_i32_32x32x32_i8(ah, b1, aH1h, 0, 0, 0);
        aH0l = __builtin_amdgcn_mfma_i32_32x32x32_i8(al, b0, aH0l, 0, 0, 0);
        aH1l = __builtin_amdgcn_mfma_i32_32x32x32_i8(al, b1, aH1l, 0, 0, 0);
      } else {
        aX0h = __builtin_amdgcn_mfma_i32_32x32x32_i8(ah, b0, aX0h, 0, 0, 0);
        aX1h = __builtin_amdgcn_mfma_i32_32x32x32_i8(ah, b1, aX1h, 0, 0, 0);
        aX0l = __builtin_amdgcn_mfma_i32_32x32x32_i8(al, b0, aX0l, 0, 0, 0);
        aX1l = __builtin_amdgcn_mfma_i32_32x32x32_i8(al, b1, aX1l, 0, 0, 0);
      }
    }
  };

  // prologue: B0..B3 (4 ops), A0..A2 (12 ops)
  stageB(0, 0); stageB(1, 1); stageB(2, 2); stageB(3, 3);
  loadA(0, 0); loadA(1, 1); loadA(2, 2);
#pragma unroll
  for (int kt = 0; kt < 33; ++kt) {
    if (kt + 4 <= 32) stageB(kt + 4, (kt + 4) % 6);   // 1 op
    if (kt + 3 <= 32) loadA(kt + 3, (kt + 3) & 3);    // 4 ops
    // exact FIFO ladder: #ops newer than A(kt)'s last op
    if (kt == 0)       asm volatile("s_waitcnt vmcnt(13)" ::: "memory");
    else if (kt == 1)  asm volatile("s_waitcnt vmcnt(14)" ::: "memory");
    else if (kt <= 28) asm volatile("s_waitcnt vmcnt(15)" ::: "memory");
    else if (kt == 29) asm volatile("s_waitcnt vmcnt(14)" ::: "memory");
    else if (kt == 30) asm volatile("s_waitcnt vmcnt(9)" ::: "memory");
    else if (kt == 31) asm volatile("s_waitcnt vmcnt(4)" ::: "memory");
    else               asm volatile("s_waitcnt vmcnt(0)" ::: "memory");
    asm volatile("s_barrier" ::: "memory");  // B(kt) resident (all waves); all
                                             // waves past compute(kt-1)
    compute(kt, kt % 6);
  }

  // ---- spill: gH = (sp/127)(aHh + aHl/254), gX = sp(aXh + aXl/254), swizzled
  {
    char* const gH = arena + 24576;
    char* const gX = arena + 57344;
    const float s0 = sp[p0 + l31], s1 = sp[p0 + 32 + l31];
#pragma unroll
    for (int cb = 0; cb < 2; ++cb) {
      const i32x16& ahh = cb ? aH1h : aH0h;
      const i32x16& ahl = cb ? aH1l : aH0l;
      const i32x16& axh = cb ? aX1h : aX0h;
      const i32x16& axl = cb ? aX1l : aX0l;
      const float spc = cb ? s1 : s0;
      const float fH = spc * (1.f / 127.f);
      const int col = cb * 32 + l31;
#pragma unroll
      for (int q = 0; q < 4; ++q) {
        f32x4 vH, vX;
#pragma unroll
        for (int e = 0; e < 4; ++e) {
          vH[e] = fH * ((float)ahh[4 * q + e] + (float)ahl[4 * q + e] * (1.f / 254.f));
          vX[e] = spc * ((float)axh[4 * q + e] + (float)axl[4 * q + e] * (1.f / 254.f));
        }
        int chunk = wv * 8 + q * 2 + lh;   // row>>2 ; row = wv*32 + q*8 + lh*4
        *(f32x4*)(gH + col * 512 + ((chunk ^ (col & 7)) << 4)) = vH;
        *(f32x4*)(gX + col * 512 + ((chunk ^ (col & 7)) << 4)) = vX;
      }
    }
  }
  __syncthreads();

  // ---- gates + state: thread -> (row bl 0..127, unit-group ug of 8 units)
  {
    const char* const gH = arena + 24576;
    const char* const gX = arena + 57344;
    const int bl = tid & 127, ug = tid >> 7;
    const int bg = b0 + bl;
    const float sxv = sx[t * 256 + bg];
    const bool emit = (t >= 127);
    float yacc = 0.f;
    union { u8 q[8]; u64 v; } hqh, hql;
#pragma unroll
    for (int j = 0; j < 8; ++j) {
      int ul = ug * 8 + j;
      float g[4];
#pragma unroll
      for (int gi = 0; gi < 4; ++gi) {
        int col = ul * 4 + gi;
        int off = col * 512 + (((bl >> 2) ^ (col & 7)) << 4) + (bl & 3) * 4;
        g[gi] = *(const float*)(gH + off) + sxv * *(const float*)(gX + off);
      }
      const float4 bs = *(const float4*)(bsum + p0 + ul * 4);
      float si = sigmoidf_(g[0] + bs.x);
      float sf = sigmoidf_(g[1] + bs.y);
      float so = sigmoidf_(g[2] + bs.z);
      float tc = tanhf_(g[3] + bs.w);
      size_t ci = (size_t)(u0 + ul) * NB + bg;
      float cn = sf * c_t[ci] + si * tc;
      float h = so * tanhf_(cn);
      c_t[ci] = cn;
      float hs = h * 127.f;
      int hi = q8(hs);
      int lo = q8((hs - (float)hi) * 254.f);
      hqh.q[j] = (u8)(signed char)hi;
      hql.q[j] = (u8)(signed char)lo;
      if (emit) yacc += h * Wout[u0 + ul];
    }
    // h -> fragment layout: rb = bg>>5, kc32 = cs>>1, lane = (cs&1)*32+(bg&31)
    size_t hoff = ((size_t)((bg >> 5) * 64 + (cs >> 1)) * 64 +
                   (cs & 1) * 32 + (bg & 31)) * 16 + ug * 8;
    *(u64*)(houtH + hoff) = hqh.v;
    *(u64*)(houtL + hoff) = hql.v;
    if (emit) ypart[((size_t)(t - 127) * 256 + cs * 2 + ug) * NB + bg] = yacc;
  }
}

// ---- y[b][j] = bout + sum_{s<256} ypart[j][s][b]
__global__ __launch_bounds__(256) void wl_finy(const float* __restrict__ ypart,
                                               const float* __restrict__ bout,
                                               float* __restrict__ out) {
  int j = blockIdx.x;
  int b = threadIdx.x;
  const float* yp = ypart + (size_t)j * 256 * NB;
  float s = bout[0];
#pragma unroll 8
  for (int i = 0; i < 256; ++i) s += yp[i * NB + b];
  out[b * NO + j] = s;
}

extern "C" void kernel_launch(void* const* d_in, const int* in_sizes, int n_in,
                              void* d_out, int out_size, void* d_ws, size_t ws_size,
                              hipStream_t stream) {
  const float* trains = (const float*)d_in[0];
  const float* dec    = (const float*)d_in[1];
  const float* Wx     = (const float*)d_in[2];
  const float* bx     = (const float*)d_in[3];
  const float* Wh     = (const float*)d_in[4];
  const float* bh     = (const float*)d_in[5];
  const float* Win    = (const float*)d_in[6];
  const float* b_in   = (const float*)d_in[7];
  const float* Wout   = (const float*)d_in[8];
  const float* bout   = (const float*)d_in[9];
  float* out = (float*)d_out;
  char* ws = (char*)d_ws;

  u8*    Wq    = (u8*)(ws);                   // 17,301,504
  float* sp    = (float*)(ws + 17301504);     //     32,768 -> 17,334,272
  float* rq    = (float*)(ws + 17334272);     //     32,768 -> 17,367,040
  float* bsum  = (float*)(ws + 17367040);     //     32,768 -> 17,399,808
  u8*    xfH   = (u8*)(ws + 17399808);        //  2,473,984 -> 19,873,792
  u8*    xfL   = (u8*)(ws + 19873792);        //  2,473,984 -> 22,347,776
  float* sx    = (float*)(ws + 22347776);     //    154,624 -> 22,502,400
  u8*    hfH   = (u8*)(ws + 23550976);        //  1,048,576 -> 24,599,552
  u8*    hfL   = (u8*)(ws + 24599552);        //  1,048,576 -> 25,648,128
  float* c_t   = (float*)(ws + 25648128);     //  2,097,152 -> 27,745,280
  float* ypart = (float*)(ws + 27745280);     //  6,291,456 -> 34,036,736
  float* pmax  = (float*)(ws + 34036736);     //    262,144 -> 34,298,880

  // zero hfH + hfL (both bufs) + c_t in one contiguous memset
  (void)hipMemsetAsync(ws + 23550976, 0, 4194304, stream);
  wl_colmax1<<<dim3(128, 8), 256, 0, stream>>>(Wx, Wh, pmax);
  wl_colmax2<<<32, 256, 0, stream>>>(pmax, sp, rq);
  wl_pack_w<<<dim3(128, 33), 256, 0, stream>>>(Wx, Wh, rq, Wq);
  wl_bsum<<<32, 256, 0, stream>>>(bx, bh, bsum);
  wl_xall<<<NSTEPS, 256, 0, stream>>>(trains, dec, Win, b_in, xfH, xfL, sx);
  for (int t = 0; t < NSTEPS; ++t)
    wl_step<<<256, 256, 0, stream>>>(Wq, bsum, sp, xfH, xfL, sx, hfH, hfL,
                                     c_t, ypart, Wout, t);
  wl_finy<<<NO, 256, 0, stream>>>(ypart, bout, out);
}